// Round 12
// baseline (802.420 us; speedup 1.0000x reference)
//
#include <hip/hip_runtime.h>

typedef __bf16 bf16_t;
typedef __attribute__((ext_vector_type(8))) __bf16 bf16x8;
typedef __attribute__((ext_vector_type(4))) float f32x4;

__device__ __forceinline__ float gelu_exact(float x) {
    return 0.5f * x * (1.0f + erff(x * 0.70710678118654752f));
}

#define AS1 __attribute__((address_space(1)))
#define AS3 __attribute__((address_space(3)))

// ---------- single-stage full-K (=192) MFMA GEMM: one barrier, no dbuf ----------
// C[m][n] = sum_k A[m][k]*B[n][k], K=192 staged entirely into LDS once.
// 256 thr = 4 waves (2x2); per-wave (BM/2)x(BN/2). LDS panels [rc|nc][kt][32r][64c]
// with zero-conflict 128B-row-stride + ch^(row&7) XOR (round-5 verified geometry).
// EPI: 1 = +bias bf16 | 2 = gelu(+bias) bf16 | 3 = fp32 resid+acc+bias
template<int BM, int BN, int EPI>
__global__ __launch_bounds__(256)
void sgemm(const bf16_t* __restrict__ A, int lda,
           const bf16_t* __restrict__ B, int ldb,
           bf16_t* __restrict__ C, int ldc,
           const float* __restrict__ bias,
           float* __restrict__ Cf, const float* __restrict__ resid)
{
    constexpr int MR = BM / 32;
    constexpr int NR = BN / 32;
    __shared__ __align__(16) bf16_t As[BM * 192];
    __shared__ __align__(16) bf16_t Bs[BN * 192];
    const int t = threadIdx.x, w = t >> 6, lane = t & 63;
    const int wr = w >> 1, wc = w & 1;
    const long n0 = (long)blockIdx.x * BN;
    const long m0 = (long)blockIdx.y * BM;

    // stage all of K: panel (rc,kt) = [32 rows][64 cols]; thread t covers
    // row rc*32+(t>>3), lds chunk t&7; source chunk inverse-swizzled ^(row&7).
    const int srow = t >> 3;
    const int schx = (t & 7) ^ (srow & 7);
    #pragma unroll
    for (int rc = 0; rc < BM / 32; ++rc)
        #pragma unroll
        for (int kt = 0; kt < 3; ++kt) {
            const bf16_t* src = A + (m0 + rc * 32 + srow) * (long)lda + kt * 64 + schx * 8;
            __builtin_amdgcn_global_load_lds((AS1 void*)(bf16_t*)src,
                (AS3 void*)(As + (rc * 3 + kt) * 2048 + w * 512), 16, 0, 0);
        }
    #pragma unroll
    for (int nc = 0; nc < BN / 32; ++nc)
        #pragma unroll
        for (int kt = 0; kt < 3; ++kt) {
            const bf16_t* src = B + (n0 + nc * 32 + srow) * (long)ldb + kt * 64 + schx * 8;
            __builtin_amdgcn_global_load_lds((AS1 void*)(bf16_t*)src,
                (AS3 void*)(Bs + (nc * 3 + kt) * 2048 + w * 512), 16, 0, 0);
        }
    asm volatile("s_waitcnt vmcnt(0)" ::: "memory");
    __builtin_amdgcn_s_barrier();   // the only barrier: no LDS reuse afterwards

    const int lrow = lane & 15, kq4 = lane >> 4;
    f32x4 acc[MR][NR] = {};
    #pragma unroll
    for (int kt = 0; kt < 3; ++kt) {
        bf16x8 af[MR][2], bfr[NR][2];
        #pragma unroll
        for (int i = 0; i < MR; ++i) {
            const int row = wr * (BM / 2) + i * 16 + lrow;
            #pragma unroll
            for (int ks = 0; ks < 2; ++ks) {
                const int sl = (ks * 4 + kq4) ^ (row & 7);
                af[i][ks] = *(const bf16x8*)(As + ((row >> 5) * 3 + kt) * 2048
                                             + (row & 31) * 64 + sl * 8);
            }
        }
        #pragma unroll
        for (int j = 0; j < NR; ++j) {
            const int row = wc * (BN / 2) + j * 16 + lrow;
            #pragma unroll
            for (int ks = 0; ks < 2; ++ks) {
                const int sl = (ks * 4 + kq4) ^ (row & 7);
                bfr[j][ks] = *(const bf16x8*)(Bs + ((row >> 5) * 3 + kt) * 2048
                                              + (row & 31) * 64 + sl * 8);
            }
        }
        #pragma unroll
        for (int ks = 0; ks < 2; ++ks)
            #pragma unroll
            for (int i = 0; i < MR; ++i)
                #pragma unroll
                for (int j = 0; j < NR; ++j)
                    acc[i][j] = __builtin_amdgcn_mfma_f32_16x16x32_bf16(
                        af[i][ks], bfr[j][ks], acc[i][j], 0, 0, 0);
    }

    // D mapping col=lane&15, row=(lane>>4)*4+reg (m89/m91-verified)
    const int ccol  = lane & 15;
    const int crow4 = (lane >> 4) * 4;
    #pragma unroll
    for (int i = 0; i < MR; ++i) {
        long rowb = m0 + wr * (BM / 2) + i * 16 + crow4;
        #pragma unroll
        for (int j = 0; j < NR; ++j) {
            long col = n0 + wc * (BN / 2) + j * 16 + ccol;
            #pragma unroll
            for (int r = 0; r < 4; ++r) {
                float v = acc[i][j][r];
                long row = rowb + r;
                if constexpr (EPI == 1) {
                    C[row * ldc + col] = (bf16_t)(v + bias[col]);
                } else if constexpr (EPI == 2) {
                    C[row * ldc + col] = (bf16_t)gelu_exact(v + bias[col]);
                } else {
                    long idx = row * ldc + col;
                    Cf[idx] = resid[idx] + v + bias[col];
                }
            }
        }
    }
}

// ---------- MFMA bf16 GEMM: BK=64, T2 XOR swizzle, dbuf + counted-vmcnt ----------
// (verified rounds 5-7; used for S/PV attention GEMMs and fc2)
template<int BM, int BN, int EPI, int SWZ>
__global__ __launch_bounds__(256)
void mgemm(const bf16_t* __restrict__ A, int lda, long aBatch,
           const bf16_t* __restrict__ B, int ldb, long bBatch,
           bf16_t* __restrict__ C, int ldc, long cBatch,
           const float* __restrict__ bias, int K,
           float* __restrict__ Cf, const float* __restrict__ resid)
{
    constexpr int MR = BM / 32;
    constexpr int NR = BN / 32;
    constexpr int LPT = BM / 32 + BN / 32;
    __shared__ __align__(16) bf16_t As[2][BM * 64];
    __shared__ __align__(16) bf16_t Bs[2][BN * 64];
    const int t    = threadIdx.x;
    const int w    = t >> 6;
    const int lane = t & 63;
    const int wr   = w >> 1, wc = w & 1;

    unsigned bx = blockIdx.x, by = blockIdx.y, bz = blockIdx.z;
    if constexpr (SWZ) {
        const unsigned gx = gridDim.x, gy = gridDim.y, gz = gridDim.z;
        unsigned lin = (bz * gy + by) * gx + bx;
        const unsigned cpx = (gx * gy * gz) >> 3;
        lin = (lin & 7) * cpx + (lin >> 3);
        bx = lin % gx; lin /= gx;
        by = lin % gy; bz = lin / gy;
    }

    const long n0 = (long)bx * BN;
    const long m0 = (long)by * BM;
    A += (long)bz * aBatch;
    B += (long)bz * bBatch;
    if constexpr (EPI != 3) C += (long)bz * cBatch;

    f32x4 acc[MR][NR] = {};

    const int srow8  = t >> 3;
    const int schunk = (t & 7) ^ (srow8 & 7);
    const int lrow = lane & 15;
    const int kq4  = lane >> 4;

    auto stage = [&](int buf, int k0) {
        #pragma unroll
        for (int c = 0; c < BM / 32; ++c) {
            const bf16_t* src = A + (m0 + c * 32 + srow8) * (long)lda + (k0 + schunk * 8);
            __builtin_amdgcn_global_load_lds(
                (AS1 void*)(bf16_t*)src,
                (AS3 void*)(As[buf] + c * 2048 + w * 512), 16, 0, 0);
        }
        #pragma unroll
        for (int c = 0; c < BN / 32; ++c) {
            const bf16_t* src = B + (n0 + c * 32 + srow8) * (long)ldb + (k0 + schunk * 8);
            __builtin_amdgcn_global_load_lds(
                (AS1 void*)(bf16_t*)src,
                (AS3 void*)(Bs[buf] + c * 2048 + w * 512), 16, 0, 0);
        }
    };

    const int nt = K >> 6;
    stage(0, 0);
    int cur = 0;
    for (int kt = 0; kt < nt; ++kt) {
        if (kt + 1 < nt) {
            stage(cur ^ 1, (kt + 1) << 6);
            if constexpr (LPT == 8)
                asm volatile("s_waitcnt vmcnt(8)" ::: "memory");
            else
                asm volatile("s_waitcnt vmcnt(6)" ::: "memory");
        } else {
            asm volatile("s_waitcnt vmcnt(0)" ::: "memory");
        }
        __builtin_amdgcn_s_barrier();

        bf16x8 af[MR][2], bfr[NR][2];
        #pragma unroll
        for (int i = 0; i < MR; ++i) {
            const int row = wr * (BM / 2) + i * 16 + lrow;
            #pragma unroll
            for (int ks = 0; ks < 2; ++ks) {
                const int ch = (ks * 4 + kq4) ^ (row & 7);
                af[i][ks] = *(const bf16x8*)(As[cur] + row * 64 + ch * 8);
            }
        }
        #pragma unroll
        for (int j = 0; j < NR; ++j) {
            const int row = wc * (BN / 2) + j * 16 + lrow;
            #pragma unroll
            for (int ks = 0; ks < 2; ++ks) {
                const int ch = (ks * 4 + kq4) ^ (row & 7);
                bfr[j][ks] = *(const bf16x8*)(Bs[cur] + row * 64 + ch * 8);
            }
        }
        #pragma unroll
        for (int ks = 0; ks < 2; ++ks)
            #pragma unroll
            for (int i = 0; i < MR; ++i)
                #pragma unroll
                for (int j = 0; j < NR; ++j)
                    acc[i][j] = __builtin_amdgcn_mfma_f32_16x16x32_bf16(
                        af[i][ks], bfr[j][ks], acc[i][j], 0, 0, 0);

        asm volatile("s_waitcnt lgkmcnt(0)" ::: "memory");
        __builtin_amdgcn_s_barrier();
        cur ^= 1;
    }

    const int ccol  = lane & 15;
    const int crow4 = (lane >> 4) * 4;
    #pragma unroll
    for (int i = 0; i < MR; ++i) {
        long rowb = m0 + wr * (BM / 2) + i * 16 + crow4;
        #pragma unroll
        for (int j = 0; j < NR; ++j) {
            long col = n0 + wc * (BN / 2) + j * 16 + ccol;
            #pragma unroll
            for (int r = 0; r < 4; ++r) {
                float v = acc[i][j][r];
                long row = rowb + r;
                if constexpr (EPI == 0) {
                    C[row * ldc + col] = (bf16_t)v;
                } else if constexpr (EPI == 1) {
                    C[row * ldc + col] = (bf16_t)(v + bias[col]);
                } else if constexpr (EPI == 2) {
                    C[row * ldc + col] = (bf16_t)gelu_exact(v + bias[col]);
                } else {
                    long idx = row * ldc + col;
                    Cf[idx] = resid[idx] + v + bias[col];
                }
            }
        }
    }
}

// Vt[h][e][m] = V[h][m][e],  V[h][m][e] = Y[m*27648 + 18432 + h*1536 + e]
__global__ __launch_bounds__(256)
void transpose_v(const bf16_t* __restrict__ Y, bf16_t* __restrict__ Vt)
{
    __shared__ bf16_t tile[64][80];
    const int h  = blockIdx.z;
    const int e0 = blockIdx.x * 64;
    const int m0 = blockIdx.y * 64;
    const int t  = threadIdx.x;
    const int lr = t >> 3;
    const int lc8 = t & 7;

    #pragma unroll
    for (int i = 0; i < 64; i += 32) {
        int row = lr + i;
        bf16x8 vv = *(const bf16x8*)(Y + (long)(m0 + row) * 27648 + 18432 + h * 1536 + e0 + lc8 * 8);
        int cs = lc8 ^ (row >> 3);
        *(bf16x8*)&tile[row][cs * 8] = vv;
    }
    __syncthreads();
    #pragma unroll
    for (int i = 0; i < 64; i += 32) {
        int er = lr + i;
        bf16x8 vv;
        #pragma unroll
        for (int j = 0; j < 8; ++j) {
            int row = lc8 * 8 + j;
            int cs = (er >> 3) ^ lc8;
            vv[j] = tile[row][cs * 8 + (er & 7)];
        }
        *(bf16x8*)(Vt + ((long)h * 1536 + e0 + er) * 2304 + m0 + lc8 * 8) = vv;
    }
}

// LayerNorm: one WAVE per 192-row, shfl reductions, zero barriers. fp32 in -> bf16 out.
__global__ __launch_bounds__(256)
void ln_fast(const float* __restrict__ x, const float* __restrict__ g,
             const float* __restrict__ b, bf16_t* __restrict__ o, int nrows)
{
    const int lane = threadIdx.x & 63;
    const int wave = threadIdx.x >> 6;
    const float g0 = g[lane], g1 = g[lane + 64], g2 = g[lane + 128];
    const float b0 = b[lane], b1 = b[lane + 64], b2 = b[lane + 128];
    for (long row = (long)blockIdx.x * 4 + wave; row < nrows; row += (long)gridDim.x * 4) {
        const float* xr = x + row * 192;
        float v0 = xr[lane], v1 = xr[lane + 64], v2 = xr[lane + 128];
        float s  = v0 + v1 + v2;
        float ss = v0 * v0 + v1 * v1 + v2 * v2;
        #pragma unroll
        for (int d = 32; d > 0; d >>= 1) {
            s  += __shfl_xor(s, d);
            ss += __shfl_xor(ss, d);
        }
        float mean = s * (1.f / 192.f);
        float var  = ss * (1.f / 192.f) - mean * mean;
        float rs   = rsqrtf(var + 1e-5f);
        bf16_t* orow = o + row * 192;
        orow[lane]       = (bf16_t)((v0 - mean) * rs * g0 + b0);
        orow[lane + 64]  = (bf16_t)((v1 - mean) * rs * g1 + b1);
        orow[lane + 128] = (bf16_t)((v2 - mean) * rs * g2 + b2);
    }
}

// softmax over 2304 bf16 logits (scale folded), in place.
__global__ __launch_bounds__(256)
void softmax_fast(bf16_t* __restrict__ S)
{
    const float SC = 0.17677669529663687f;
    __shared__ float wmax[4], wsum[4];
    const long base = (long)blockIdx.x * 2304;
    const int t = threadIdx.x;
    const int lane = t & 63, w = t >> 6;
    float v[9];
    float mx = -1e30f;
    #pragma unroll
    for (int i = 0; i < 9; ++i) {
        v[i] = (float)S[base + t + i * 256] * SC;
        mx = fmaxf(mx, v[i]);
    }
    #pragma unroll
    for (int d = 32; d > 0; d >>= 1) mx = fmaxf(mx, __shfl_xor(mx, d));
    if (lane == 0) wmax[w] = mx;
    __syncthreads();
    mx = fmaxf(fmaxf(wmax[0], wmax[1]), fmaxf(wmax[2], wmax[3]));
    float sum = 0.f;
    #pragma unroll
    for (int i = 0; i < 9; ++i) { v[i] = __expf(v[i] - mx); sum += v[i]; }
    #pragma unroll
    for (int d = 32; d > 0; d >>= 1) sum += __shfl_xor(sum, d);
    if (lane == 0) wsum[w] = sum;
    __syncthreads();
    const float inv = 1.f / (wsum[0] + wsum[1] + wsum[2] + wsum[3]);
    #pragma unroll
    for (int i = 0; i < 9; ++i) S[base + t + i * 256] = (bf16_t)(v[i] * inv);
}

// all four weight casts in one launch
__global__ __launch_bounds__(256)
void cast_all(const float* __restrict__ w0, const float* __restrict__ w1,
              const float* __restrict__ w2, const float* __restrict__ w3,
              bf16_t* __restrict__ o0, bf16_t* __restrict__ o1,
              bf16_t* __restrict__ o2, bf16_t* __restrict__ o3)
{
    int i = blockIdx.x * 256 + threadIdx.x;
    if (i < 110592)       o0[i] = (bf16_t)w0[i];
    else if (i < 147456)  o1[i - 110592] = (bf16_t)w1[i - 110592];
    else if (i < 294912)  o2[i - 147456] = (bf16_t)w2[i - 147456];
    else if (i < 442368)  o3[i - 294912] = (bf16_t)w3[i - 294912];
}

extern "C" void kernel_launch(void* const* d_in, const int* in_sizes, int n_in,
                              void* d_out, int out_size, void* d_ws, size_t ws_size,
                              hipStream_t stream)
{
    (void)in_sizes; (void)n_in; (void)out_size; (void)ws_size;
    const float* x      = (const float*)d_in[0];
    const float* n1g    = (const float*)d_in[1];
    const float* n1b    = (const float*)d_in[2];
    const float* qkv_w  = (const float*)d_in[3];
    const float* qkv_b  = (const float*)d_in[4];
    const float* proj_w = (const float*)d_in[5];
    const float* proj_b = (const float*)d_in[6];
    const float* n2g    = (const float*)d_in[7];
    const float* n2b    = (const float*)d_in[8];
    const float* fc1_w  = (const float*)d_in[9];
    const float* fc1_b  = (const float*)d_in[10];
    const float* fc2_w  = (const float*)d_in[11];
    const float* fc2_b  = (const float*)d_in[12];
    float* out = (float*)d_out;

    char* ws = (char*)d_ws;
    size_t off = 0;
    auto alloc = [&](size_t nbytes) -> void* {
        off = (off + 255) & ~(size_t)255;
        void* p = ws + off;
        off += nbytes;
        return p;
    };

    bf16_t* Wq   = (bf16_t*)alloc((size_t)576 * 192 * 2);
    bf16_t* Wp   = (bf16_t*)alloc((size_t)192 * 192 * 2);
    bf16_t* W1   = (bf16_t*)alloc((size_t)768 * 192 * 2);
    bf16_t* W2   = (bf16_t*)alloc((size_t)192 * 768 * 2);
    bf16_t* Hbuf = (bf16_t*)alloc((size_t)110592 * 192 * 2);
    bf16_t* Qkv  = (bf16_t*)alloc((size_t)110592 * 768 * 2);
    bf16_t* Vt   = Qkv + (size_t)110592 * 576;
    bf16_t* Sbuf = (bf16_t*)d_out;

    cast_all<<<1728, 256, 0, stream>>>(qkv_w, proj_w, fc1_w, fc2_w, Wq, Wp, W1, W2);

    // LN1: x -> Hbuf (bf16)
    ln_fast<<<2048, 256, 0, stream>>>(x, n1g, n1b, Hbuf, 110592);
    // QKV: (110592x192)@(576x192)^T + b -> Qkv   [single-stage K=192]
    sgemm<96, 64, 1><<<dim3(9, 1152, 1), 256, 0, stream>>>(
        Hbuf, 192, Wq, 192, Qkv, 576, qkv_b, nullptr, nullptr);
    // Vt[h][e][m] = V[h][m][e]
    transpose_v<<<dim3(24, 36, 6), 256, 0, stream>>>(Qkv, Vt);
    // S = Q @ K^T per head: 2304x2304, K=1536   [grid 1944 % 8 == 0]
    mgemm<128, 128, 0, 1><<<dim3(18, 18, 6), 256, 0, stream>>>(
        Qkv, 27648, 1536, Qkv + 9216, 27648, 1536,
        Sbuf, 2304, (long)2304 * 2304, nullptr, 1536, nullptr, nullptr);
    // softmax rows (scale inside), in place
    softmax_fast<<<13824, 256, 0, stream>>>(Sbuf);
    // O = P @ Vt^T per head: 2304x1536, K=2304  [grid 1296 % 8 == 0]
    mgemm<128, 128, 0, 1><<<dim3(12, 18, 6), 256, 0, stream>>>(
        Sbuf, 2304, (long)2304 * 2304, Vt, 2304, (long)1536 * 2304,
        Hbuf, 9216, 1536, nullptr, 2304, nullptr, nullptr);
    // x1 = x + O @ Wp^T + pb -> out (fp32)      [single-stage K=192]
    sgemm<96, 64, 3><<<dim3(3, 1152, 1), 256, 0, stream>>>(
        Hbuf, 192, Wp, 192, nullptr, 192, proj_b, out, x);
    // LN2: x1 -> Hbuf (bf16)
    ln_fast<<<2048, 256, 0, stream>>>(out, n2g, n2b, Hbuf, 110592);
    // fc1 + gelu -> Qkv (768 cols)              [single-stage K=192]
    sgemm<96, 64, 2><<<dim3(12, 1152, 1), 256, 0, stream>>>(
        Hbuf, 192, W1, 192, Qkv, 768, fc1_b, nullptr, nullptr);
    // fc2 + resid -> out (fp32, in-place resid) [K=768, dbuf mgemm]
    mgemm<128, 64, 3, 0><<<dim3(3, 864, 1), 256, 0, stream>>>(
        Qkv, 768, 0, W2, 768, 0, nullptr, 192, 0, fc2_b, 768, out, out);
}

// Round 13
// 785.915 us; speedup vs baseline: 1.0210x; 1.0210x over previous
//
#include <hip/hip_runtime.h>

typedef __bf16 bf16_t;
typedef __attribute__((ext_vector_type(8))) __bf16 bf16x8;
typedef __attribute__((ext_vector_type(4))) float f32x4;

__device__ __forceinline__ float gelu_exact(float x) {
    return 0.5f * x * (1.0f + erff(x * 0.70710678118654752f));
}

#define AS1 __attribute__((address_space(1)))
#define AS3 __attribute__((address_space(3)))

// ---------- MFMA bf16 GEMM: BK=64, T2 XOR swizzle, dbuf + counted-vmcnt ----------
// (verified rounds 5-7/12; used for qkv, S, PV, fc1, fc2)
template<int BM, int BN, int EPI, int SWZ>
__global__ __launch_bounds__(256)
void mgemm(const bf16_t* __restrict__ A, int lda, long aBatch,
           const bf16_t* __restrict__ B, int ldb, long bBatch,
           bf16_t* __restrict__ C, int ldc, long cBatch,
           const float* __restrict__ bias, int K,
           float* __restrict__ Cf, const float* __restrict__ resid)
{
    constexpr int MR = BM / 32;
    constexpr int NR = BN / 32;
    constexpr int LPT = BM / 32 + BN / 32;
    __shared__ __align__(16) bf16_t As[2][BM * 64];
    __shared__ __align__(16) bf16_t Bs[2][BN * 64];
    const int t    = threadIdx.x;
    const int w    = t >> 6;
    const int lane = t & 63;
    const int wr   = w >> 1, wc = w & 1;

    unsigned bx = blockIdx.x, by = blockIdx.y, bz = blockIdx.z;
    if constexpr (SWZ) {
        const unsigned gx = gridDim.x, gy = gridDim.y, gz = gridDim.z;
        unsigned lin = (bz * gy + by) * gx + bx;
        const unsigned cpx = (gx * gy * gz) >> 3;
        lin = (lin & 7) * cpx + (lin >> 3);
        bx = lin % gx; lin /= gx;
        by = lin % gy; bz = lin / gy;
    }

    const long n0 = (long)bx * BN;
    const long m0 = (long)by * BM;
    A += (long)bz * aBatch;
    B += (long)bz * bBatch;
    if constexpr (EPI != 3) C += (long)bz * cBatch;

    f32x4 acc[MR][NR] = {};

    const int srow8  = t >> 3;
    const int schunk = (t & 7) ^ (srow8 & 7);
    const int lrow = lane & 15;
    const int kq4  = lane >> 4;

    auto stage = [&](int buf, int k0) {
        #pragma unroll
        for (int c = 0; c < BM / 32; ++c) {
            const bf16_t* src = A + (m0 + c * 32 + srow8) * (long)lda + (k0 + schunk * 8);
            __builtin_amdgcn_global_load_lds(
                (AS1 void*)(bf16_t*)src,
                (AS3 void*)(As[buf] + c * 2048 + w * 512), 16, 0, 0);
        }
        #pragma unroll
        for (int c = 0; c < BN / 32; ++c) {
            const bf16_t* src = B + (n0 + c * 32 + srow8) * (long)ldb + (k0 + schunk * 8);
            __builtin_amdgcn_global_load_lds(
                (AS1 void*)(bf16_t*)src,
                (AS3 void*)(Bs[buf] + c * 2048 + w * 512), 16, 0, 0);
        }
    };

    const int nt = K >> 6;
    stage(0, 0);
    int cur = 0;
    for (int kt = 0; kt < nt; ++kt) {
        if (kt + 1 < nt) {
            stage(cur ^ 1, (kt + 1) << 6);
            if constexpr (LPT == 8)
                asm volatile("s_waitcnt vmcnt(8)" ::: "memory");
            else
                asm volatile("s_waitcnt vmcnt(6)" ::: "memory");
        } else {
            asm volatile("s_waitcnt vmcnt(0)" ::: "memory");
        }
        __builtin_amdgcn_s_barrier();

        bf16x8 af[MR][2], bfr[NR][2];
        #pragma unroll
        for (int i = 0; i < MR; ++i) {
            const int row = wr * (BM / 2) + i * 16 + lrow;
            #pragma unroll
            for (int ks = 0; ks < 2; ++ks) {
                const int ch = (ks * 4 + kq4) ^ (row & 7);
                af[i][ks] = *(const bf16x8*)(As[cur] + row * 64 + ch * 8);
            }
        }
        #pragma unroll
        for (int j = 0; j < NR; ++j) {
            const int row = wc * (BN / 2) + j * 16 + lrow;
            #pragma unroll
            for (int ks = 0; ks < 2; ++ks) {
                const int ch = (ks * 4 + kq4) ^ (row & 7);
                bfr[j][ks] = *(const bf16x8*)(Bs[cur] + row * 64 + ch * 8);
            }
        }
        #pragma unroll
        for (int ks = 0; ks < 2; ++ks)
            #pragma unroll
            for (int i = 0; i < MR; ++i)
                #pragma unroll
                for (int j = 0; j < NR; ++j)
                    acc[i][j] = __builtin_amdgcn_mfma_f32_16x16x32_bf16(
                        af[i][ks], bfr[j][ks], acc[i][j], 0, 0, 0);

        asm volatile("s_waitcnt lgkmcnt(0)" ::: "memory");
        __builtin_amdgcn_s_barrier();
        cur ^= 1;
    }

    const int ccol  = lane & 15;
    const int crow4 = (lane >> 4) * 4;
    #pragma unroll
    for (int i = 0; i < MR; ++i) {
        long rowb = m0 + wr * (BM / 2) + i * 16 + crow4;
        #pragma unroll
        for (int j = 0; j < NR; ++j) {
            long col = n0 + wc * (BN / 2) + j * 16 + ccol;
            #pragma unroll
            for (int r = 0; r < 4; ++r) {
                float v = acc[i][j][r];
                long row = rowb + r;
                if constexpr (EPI == 0) {
                    C[row * ldc + col] = (bf16_t)v;
                } else if constexpr (EPI == 1) {
                    C[row * ldc + col] = (bf16_t)(v + bias[col]);
                } else if constexpr (EPI == 2) {
                    C[row * ldc + col] = (bf16_t)gelu_exact(v + bias[col]);
                } else {
                    long idx = row * ldc + col;
                    Cf[idx] = resid[idx] + v + bias[col];
                }
            }
        }
    }
}

// ---------- fused proj + residual + LayerNorm2 ----------
// One block = 64 rows x ALL 192 cols of x1 = x + O@Wp^T + pb.
// Writes x1 (fp32) to out AND LN(x1) (bf16) to H, killing the separate LN2 pass.
// dbuf mgemm body (BM=64, BN=192, K=192, LPT=8); x1 tile parked in LDS (aliased
// onto dead staging buffers, stride 196 floats = 2-way banks) for the row stats.
__global__ __launch_bounds__(256)
void proj_ln(const bf16_t* __restrict__ A,            // O (110592x192 view)
             const bf16_t* __restrict__ B,            // Wp bf16 (192x192)
             const float* __restrict__ bias,          // proj_b
             const float* __restrict__ resid,         // x
             float* __restrict__ out,                 // x1 fp32
             const float* __restrict__ g, const float* __restrict__ bb,
             bf16_t* __restrict__ H)                  // LN2 output bf16
{
    constexpr int MR = 2, NR = 6;                     // wave tile 32x96
    __shared__ __align__(16) char smem[65536];
    bf16_t* As = (bf16_t*)smem;                       // [2][64*64]
    bf16_t* Bs = (bf16_t*)(smem + 16384);             // [2][192*64]
    float*  Xs = (float*)smem;                        // [64][196] after K-loop
    const int t = threadIdx.x, w = t >> 6, lane = t & 63;
    const int wr = w >> 1, wc = w & 1;
    const long m0 = (long)blockIdx.x * 64;

    const int srow8  = t >> 3;
    const int schunk = (t & 7) ^ (srow8 & 7);
    const int lrow = lane & 15, kq4 = lane >> 4;

    auto stage = [&](int buf, int k0) {
        #pragma unroll
        for (int c = 0; c < 2; ++c) {
            const bf16_t* src = A + (m0 + c * 32 + srow8) * 192L + (k0 + schunk * 8);
            __builtin_amdgcn_global_load_lds((AS1 void*)(bf16_t*)src,
                (AS3 void*)(As + buf * 4096 + c * 2048 + w * 512), 16, 0, 0);
        }
        #pragma unroll
        for (int c = 0; c < 6; ++c) {
            const bf16_t* src = B + (c * 32 + srow8) * 192L + (k0 + schunk * 8);
            __builtin_amdgcn_global_load_lds((AS1 void*)(bf16_t*)src,
                (AS3 void*)(Bs + buf * 12288 + c * 2048 + w * 512), 16, 0, 0);
        }
    };

    f32x4 acc[MR][NR] = {};
    stage(0, 0);
    int cur = 0;
    for (int kt = 0; kt < 3; ++kt) {
        if (kt < 2) {
            stage(cur ^ 1, (kt + 1) * 64);
            asm volatile("s_waitcnt vmcnt(8)" ::: "memory");
        } else {
            asm volatile("s_waitcnt vmcnt(0)" ::: "memory");
        }
        __builtin_amdgcn_s_barrier();

        bf16x8 af[MR][2], bfr[NR][2];
        #pragma unroll
        for (int i = 0; i < MR; ++i) {
            const int row = wr * 32 + i * 16 + lrow;
            #pragma unroll
            for (int ks = 0; ks < 2; ++ks) {
                const int ch = (ks * 4 + kq4) ^ (row & 7);
                af[i][ks] = *(const bf16x8*)(As + cur * 4096 + row * 64 + ch * 8);
            }
        }
        #pragma unroll
        for (int j = 0; j < NR; ++j) {
            const int row = wc * 96 + j * 16 + lrow;
            #pragma unroll
            for (int ks = 0; ks < 2; ++ks) {
                const int ch = (ks * 4 + kq4) ^ (row & 7);
                bfr[j][ks] = *(const bf16x8*)(Bs + cur * 12288 + row * 64 + ch * 8);
            }
        }
        #pragma unroll
        for (int ks = 0; ks < 2; ++ks)
            #pragma unroll
            for (int i = 0; i < MR; ++i)
                #pragma unroll
                for (int j = 0; j < NR; ++j)
                    acc[i][j] = __builtin_amdgcn_mfma_f32_16x16x32_bf16(
                        af[i][ks], bfr[j][ks], acc[i][j], 0, 0, 0);

        asm volatile("s_waitcnt lgkmcnt(0)" ::: "memory");
        __builtin_amdgcn_s_barrier();
        cur ^= 1;
    }

    // epilogue: x1 -> out (fp32) and Xs (LDS, staging dead after final barrier)
    const int ccol = lane & 15, crow4 = (lane >> 4) * 4;
    #pragma unroll
    for (int i = 0; i < MR; ++i) {
        const int rl = wr * 32 + i * 16 + crow4;
        #pragma unroll
        for (int j = 0; j < NR; ++j) {
            const int col = wc * 96 + j * 16 + ccol;
            #pragma unroll
            for (int r = 0; r < 4; ++r) {
                long idx = (m0 + rl + r) * 192L + col;
                float v = resid[idx] + acc[i][j][r] + bias[col];
                out[idx] = v;
                Xs[(rl + r) * 196 + col] = v;
            }
        }
    }
    __syncthreads();

    // LN2: row = t>>2, quarter (t&3) covers 48 cols; 4-lane shfl reduce.
    {
        const int row = t >> 2, q = t & 3;
        const float* xr = Xs + row * 196 + q * 48;
        float s = 0.f, ss = 0.f;
        #pragma unroll
        for (int c = 0; c < 48; ++c) { float v = xr[c]; s += v; ss += v * v; }
        s += __shfl_xor(s, 1); ss += __shfl_xor(ss, 1);
        s += __shfl_xor(s, 2); ss += __shfl_xor(ss, 2);
        const float mean = s * (1.f / 192.f);
        const float var  = ss * (1.f / 192.f) - mean * mean;
        const float rs   = rsqrtf(var + 1e-5f);
        bf16_t* hr = H + (m0 + row) * 192 + q * 48;
        const float* gq = g + q * 48;
        const float* bq = bb + q * 48;
        #pragma unroll
        for (int c = 0; c < 48; ++c)
            hr[c] = (bf16_t)((xr[c] - mean) * rs * gq[c] + bq[c]);
    }
}

// Vt[h][e][m] = V[h][m][e],  V[h][m][e] = Y[m*27648 + 18432 + h*1536 + e]
__global__ __launch_bounds__(256)
void transpose_v(const bf16_t* __restrict__ Y, bf16_t* __restrict__ Vt)
{
    __shared__ bf16_t tile[64][80];
    const int h  = blockIdx.z;
    const int e0 = blockIdx.x * 64;
    const int m0 = blockIdx.y * 64;
    const int t  = threadIdx.x;
    const int lr = t >> 3;
    const int lc8 = t & 7;

    #pragma unroll
    for (int i = 0; i < 64; i += 32) {
        int row = lr + i;
        bf16x8 vv = *(const bf16x8*)(Y + (long)(m0 + row) * 27648 + 18432 + h * 1536 + e0 + lc8 * 8);
        int cs = lc8 ^ (row >> 3);
        *(bf16x8*)&tile[row][cs * 8] = vv;
    }
    __syncthreads();
    #pragma unroll
    for (int i = 0; i < 64; i += 32) {
        int er = lr + i;
        bf16x8 vv;
        #pragma unroll
        for (int j = 0; j < 8; ++j) {
            int row = lc8 * 8 + j;
            int cs = (er >> 3) ^ lc8;
            vv[j] = tile[row][cs * 8 + (er & 7)];
        }
        *(bf16x8*)(Vt + ((long)h * 1536 + e0 + er) * 2304 + m0 + lc8 * 8) = vv;
    }
}

// LayerNorm: one WAVE per 192-row, shfl reductions, zero barriers. fp32 in -> bf16 out.
__global__ __launch_bounds__(256)
void ln_fast(const float* __restrict__ x, const float* __restrict__ g,
             const float* __restrict__ b, bf16_t* __restrict__ o, int nrows)
{
    const int lane = threadIdx.x & 63;
    const int wave = threadIdx.x >> 6;
    const float g0 = g[lane], g1 = g[lane + 64], g2 = g[lane + 128];
    const float b0 = b[lane], b1 = b[lane + 64], b2 = b[lane + 128];
    for (long row = (long)blockIdx.x * 4 + wave; row < nrows; row += (long)gridDim.x * 4) {
        const float* xr = x + row * 192;
        float v0 = xr[lane], v1 = xr[lane + 64], v2 = xr[lane + 128];
        float s  = v0 + v1 + v2;
        float ss = v0 * v0 + v1 * v1 + v2 * v2;
        #pragma unroll
        for (int d = 32; d > 0; d >>= 1) {
            s  += __shfl_xor(s, d);
            ss += __shfl_xor(ss, d);
        }
        float mean = s * (1.f / 192.f);
        float var  = ss * (1.f / 192.f) - mean * mean;
        float rs   = rsqrtf(var + 1e-5f);
        bf16_t* orow = o + row * 192;
        orow[lane]       = (bf16_t)((v0 - mean) * rs * g0 + b0);
        orow[lane + 64]  = (bf16_t)((v1 - mean) * rs * g1 + b1);
        orow[lane + 128] = (bf16_t)((v2 - mean) * rs * g2 + b2);
    }
}

// softmax over 2304 bf16 logits (scale folded), in place.
__global__ __launch_bounds__(256)
void softmax_fast(bf16_t* __restrict__ S)
{
    const float SC = 0.17677669529663687f;
    __shared__ float wmax[4], wsum[4];
    const long base = (long)blockIdx.x * 2304;
    const int t = threadIdx.x;
    const int lane = t & 63, w = t >> 6;
    float v[9];
    float mx = -1e30f;
    #pragma unroll
    for (int i = 0; i < 9; ++i) {
        v[i] = (float)S[base + t + i * 256] * SC;
        mx = fmaxf(mx, v[i]);
    }
    #pragma unroll
    for (int d = 32; d > 0; d >>= 1) mx = fmaxf(mx, __shfl_xor(mx, d));
    if (lane == 0) wmax[w] = mx;
    __syncthreads();
    mx = fmaxf(fmaxf(wmax[0], wmax[1]), fmaxf(wmax[2], wmax[3]));
    float sum = 0.f;
    #pragma unroll
    for (int i = 0; i < 9; ++i) { v[i] = __expf(v[i] - mx); sum += v[i]; }
    #pragma unroll
    for (int d = 32; d > 0; d >>= 1) sum += __shfl_xor(sum, d);
    if (lane == 0) wsum[w] = sum;
    __syncthreads();
    const float inv = 1.f / (wsum[0] + wsum[1] + wsum[2] + wsum[3]);
    #pragma unroll
    for (int i = 0; i < 9; ++i) S[base + t + i * 256] = (bf16_t)(v[i] * inv);
}

// all four weight casts in one launch
__global__ __launch_bounds__(256)
void cast_all(const float* __restrict__ w0, const float* __restrict__ w1,
              const float* __restrict__ w2, const float* __restrict__ w3,
              bf16_t* __restrict__ o0, bf16_t* __restrict__ o1,
              bf16_t* __restrict__ o2, bf16_t* __restrict__ o3)
{
    int i = blockIdx.x * 256 + threadIdx.x;
    if (i < 110592)       o0[i] = (bf16_t)w0[i];
    else if (i < 147456)  o1[i - 110592] = (bf16_t)w1[i - 110592];
    else if (i < 294912)  o2[i - 147456] = (bf16_t)w2[i - 147456];
    else if (i < 442368)  o3[i - 294912] = (bf16_t)w3[i - 294912];
}

extern "C" void kernel_launch(void* const* d_in, const int* in_sizes, int n_in,
                              void* d_out, int out_size, void* d_ws, size_t ws_size,
                              hipStream_t stream)
{
    (void)in_sizes; (void)n_in; (void)out_size; (void)ws_size;
    const float* x      = (const float*)d_in[0];
    const float* n1g    = (const float*)d_in[1];
    const float* n1b    = (const float*)d_in[2];
    const float* qkv_w  = (const float*)d_in[3];
    const float* qkv_b  = (const float*)d_in[4];
    const float* proj_w = (const float*)d_in[5];
    const float* proj_b = (const float*)d_in[6];
    const float* n2g    = (const float*)d_in[7];
    const float* n2b    = (const float*)d_in[8];
    const float* fc1_w  = (const float*)d_in[9];
    const float* fc1_b  = (const float*)d_in[10];
    const float* fc2_w  = (const float*)d_in[11];
    const float* fc2_b  = (const float*)d_in[12];
    float* out = (float*)d_out;

    char* ws = (char*)d_ws;
    size_t off = 0;
    auto alloc = [&](size_t nbytes) -> void* {
        off = (off + 255) & ~(size_t)255;
        void* p = ws + off;
        off += nbytes;
        return p;
    };

    bf16_t* Wq   = (bf16_t*)alloc((size_t)576 * 192 * 2);
    bf16_t* Wp   = (bf16_t*)alloc((size_t)192 * 192 * 2);
    bf16_t* W1   = (bf16_t*)alloc((size_t)768 * 192 * 2);
    bf16_t* W2   = (bf16_t*)alloc((size_t)192 * 768 * 2);
    bf16_t* Hbuf = (bf16_t*)alloc((size_t)110592 * 192 * 2);
    bf16_t* Qkv  = (bf16_t*)alloc((size_t)110592 * 768 * 2);
    bf16_t* Vt   = Qkv + (size_t)110592 * 576;
    bf16_t* Sbuf = (bf16_t*)d_out;

    cast_all<<<1728, 256, 0, stream>>>(qkv_w, proj_w, fc1_w, fc2_w, Wq, Wp, W1, W2);

    // LN1: x -> Hbuf (bf16)
    ln_fast<<<2048, 256, 0, stream>>>(x, n1g, n1b, Hbuf, 110592);
    // QKV: (110592x192)@(576x192)^T + b -> Qkv
    mgemm<128, 64, 1, 0><<<dim3(9, 864, 1), 256, 0, stream>>>(
        Hbuf, 192, 0, Wq, 192, 0, Qkv, 576, 0, qkv_b, 192, nullptr, nullptr);
    // Vt[h][e][m] = V[h][m][e]
    transpose_v<<<dim3(24, 36, 6), 256, 0, stream>>>(Qkv, Vt);
    // S = Q @ K^T per head: 2304x2304, K=1536   [grid 1944 % 8 == 0]
    mgemm<128, 128, 0, 1><<<dim3(18, 18, 6), 256, 0, stream>>>(
        Qkv, 27648, 1536, Qkv + 9216, 27648, 1536,
        Sbuf, 2304, (long)2304 * 2304, nullptr, 1536, nullptr, nullptr);
    // softmax rows (scale inside), in place
    softmax_fast<<<13824, 256, 0, stream>>>(Sbuf);
    // O = P @ Vt^T per head: 2304x1536, K=2304  [grid 1296 % 8 == 0]
    mgemm<128, 128, 0, 1><<<dim3(12, 18, 6), 256, 0, stream>>>(
        Sbuf, 2304, (long)2304 * 2304, Vt, 2304, (long)1536 * 2304,
        Hbuf, 9216, 1536, nullptr, 2304, nullptr, nullptr);
    // x1 = x + O @ Wp^T + pb -> out (fp32) AND LN2(x1) -> Hbuf (bf16), fused
    proj_ln<<<1728, 256, 0, stream>>>(
        Hbuf, Wp, proj_b, x, out, n2g, n2b, Hbuf);
    // fc1 + gelu -> Qkv (768 cols)
    mgemm<128, 128, 2, 0><<<dim3(6, 864, 1), 256, 0, stream>>>(
        Hbuf, 192, 0, W1, 192, 0, Qkv, 768, 0, fc1_b, 192, nullptr, nullptr);
    // fc2 + resid -> out (fp32, in-place resid)
    mgemm<128, 64, 3, 0><<<dim3(3, 864, 1), 256, 0, stream>>>(
        Qkv, 768, 0, W2, 768, 0, nullptr, 192, 0, fc2_b, 768, out, out);
}